// Round 1
// baseline (1939.490 us; speedup 1.0000x reference)
//
#include <hip/hip_runtime.h>
#include <hip/hip_bf16.h>
#include <stdint.h>

#define NUM_FF 7
#define DM 512
#define CARRY 384
#define RD 128
#define VOCABN 128
#define BATCH 128
#define TLEN 1024

// ---- pack ff: ffp[l][k][j] bit i = (ff[l][32k+i][j] > 0) ----
__global__ void pack_ff_kernel(const float* __restrict__ ff, uint32_t* __restrict__ ffp) {
    int idx = blockIdx.x * blockDim.x + threadIdx.x;
    if (idx >= NUM_FF * 16 * DM) return;
    int j = idx & (DM - 1);
    int k = (idx >> 9) & 15;
    int l = idx >> 13;
    const float* base = ff + (size_t)l * DM * DM + (size_t)(k * 32) * DM + j;
    uint32_t w = 0;
#pragma unroll
    for (int i = 0; i < 32; ++i)
        w |= (base[(size_t)i * DM] > 0.0f ? 1u : 0u) << i;
    ffp[idx] = w;
}

// ---- pack embed/head/initial (512 threads, 1 block) ----
__global__ void pack_small_kernel(const float* __restrict__ embed,
                                  const float* __restrict__ head,
                                  const float* __restrict__ initial,
                                  uint32_t* __restrict__ embp,
                                  uint32_t* __restrict__ headp,
                                  uint32_t* __restrict__ initp) {
    int idx = threadIdx.x; // 512
    {   // embp[v*4+k] bit i = embed[v][32k+i] > 0
        int v = idx >> 2, k = idx & 3;
        uint32_t w = 0;
#pragma unroll
        for (int i = 0; i < 32; ++i)
            w |= (embed[v * RD + k * 32 + i] > 0.0f ? 1u : 0u) << i;
        embp[idx] = w;
    }
    {   // headp[k*128+v] bit i = head[32k+i][v] > 0
        int k = idx >> 7, v = idx & 127;
        uint32_t w = 0;
#pragma unroll
        for (int i = 0; i < 32; ++i)
            w |= (head[(k * 32 + i) * VOCABN + v] > 0.0f ? 1u : 0u) << i;
        headp[idx] = w;
    }
    if (idx < 16) {
        uint32_t w = 0;
#pragma unroll
        for (int i = 0; i < 32; ++i)
            w |= (initial[idx * 32 + i] > 0.0f ? 1u : 0u) << i;
        initp[idx] = w;
    }
}

// ---- main persistent RNN kernel: 1 workgroup (512 thr) per batch row ----
__launch_bounds__(512, 2)
__global__ void brnn_kernel(const int* __restrict__ tokens,
                            const float* __restrict__ ff_thresh,
                            const uint32_t* __restrict__ ffp,
                            const uint32_t* __restrict__ embp,
                            const uint32_t* __restrict__ headp,
                            const uint32_t* __restrict__ initp,
                            float* __restrict__ out) {
    const int b = blockIdx.x;
    const int tid = threadIdx.x;
    const int wave = tid >> 6;
    const int lane = tid & 63;

    __shared__ uint32_t xbuf[2][16];
    __shared__ uint32_t hx[4];
    __shared__ uint32_t emb_lds[VOCABN * 4];
    __shared__ uint32_t head_lds[4 * VOCABN];
    __shared__ int tok_lds[TLEN];

    // per-thread weights: output column `tid`, all 7 layers, 16 words each
    uint32_t w[NUM_FF][16];
#pragma unroll
    for (int l = 0; l < NUM_FF; ++l)
#pragma unroll
        for (int k = 0; k < 16; ++k)
            w[l][k] = ffp[l * (16 * DM) + k * DM + tid];
    float th[NUM_FF];
#pragma unroll
    for (int l = 0; l < NUM_FF; ++l)
        th[l] = ff_thresh[l * DM + tid];

    emb_lds[tid] = embp[tid];
    head_lds[tid] = headp[tid];
    tok_lds[tid] = tokens[b * TLEN + tid];
    tok_lds[tid + 512] = tokens[b * TLEN + tid + 512];
    if (tid < 16) xbuf[0][tid] = initp[tid];
    __syncthreads();
    if (tid < 4) xbuf[0][12 + tid] = emb_lds[tok_lds[0] * 4 + tid];
    __syncthreads();

    int p = 0;
    float* outb = out + (size_t)b * TLEN * VOCABN;

    for (int t = 0; t < TLEN; ++t) {
#pragma unroll
        for (int l = 0; l < NUM_FF; ++l) {
            const uint4* xb = (const uint4*)xbuf[p];
            uint4 xa = xb[0], xc = xb[1], xd = xb[2], xe = xb[3];
            int a0 = __popc(xa.x ^ w[l][0]);
            a0 += __popc(xa.y ^ w[l][1]);
            a0 += __popc(xa.z ^ w[l][2]);
            a0 += __popc(xa.w ^ w[l][3]);
            int a1 = __popc(xc.x ^ w[l][4]);
            a1 += __popc(xc.y ^ w[l][5]);
            a1 += __popc(xc.z ^ w[l][6]);
            a1 += __popc(xc.w ^ w[l][7]);
            int a2 = __popc(xd.x ^ w[l][8]);
            a2 += __popc(xd.y ^ w[l][9]);
            a2 += __popc(xd.z ^ w[l][10]);
            a2 += __popc(xd.w ^ w[l][11]);
            int a3 = __popc(xe.x ^ w[l][12]);
            a3 += __popc(xe.y ^ w[l][13]);
            a3 += __popc(xe.z ^ w[l][14]);
            a3 += __popc(xe.w ^ w[l][15]);
            int acc = (a0 + a1) + (a2 + a3);
            bool bit = (float)(DM - 2 * acc) >= th[l];
            unsigned long long m = __ballot(bit);
            if (l < NUM_FF - 1) {
                if (lane == 0) {
                    xbuf[p ^ 1][2 * wave] = (uint32_t)m;
                    xbuf[p ^ 1][2 * wave + 1] = (uint32_t)(m >> 32);
                }
            } else {
                if (lane == 0) {
                    if (wave < 6) {
                        xbuf[p ^ 1][2 * wave] = (uint32_t)m;
                        xbuf[p ^ 1][2 * wave + 1] = (uint32_t)(m >> 32);
                    } else {
                        hx[2 * (wave - 6)] = (uint32_t)m;
                        hx[2 * (wave - 6) + 1] = (uint32_t)(m >> 32);
                    }
                }
                // stage next step's embedding into the carry buffer
                if (tid < 4 && t + 1 < TLEN)
                    xbuf[p ^ 1][12 + tid] = emb_lds[tok_lds[t + 1] * 4 + tid];
            }
            __syncthreads();
            p ^= 1;
        }
        // head readout from final x words 12..15 (in hx)
        if (tid < VOCABN) {
            uint32_t h0 = head_lds[0 * VOCABN + tid];
            uint32_t h1 = head_lds[1 * VOCABN + tid];
            uint32_t h2 = head_lds[2 * VOCABN + tid];
            uint32_t h3 = head_lds[3 * VOCABN + tid];
            int hc = __popc(hx[0] ^ h0);
            hc += __popc(hx[1] ^ h1);
            hc += __popc(hx[2] ^ h2);
            hc += __popc(hx[3] ^ h3);
            outb[t * VOCABN + tid] = (float)(RD - 2 * hc);
        }
    }
}

extern "C" void kernel_launch(void* const* d_in, const int* in_sizes, int n_in,
                              void* d_out, int out_size, void* d_ws, size_t ws_size,
                              hipStream_t stream) {
    const int* tokens = (const int*)d_in[0];
    const float* initial = (const float*)d_in[1];
    const float* embed = (const float*)d_in[2];
    const float* ff = (const float*)d_in[3];
    const float* ff_thresh = (const float*)d_in[4];
    const float* head = (const float*)d_in[5];
    float* out = (float*)d_out;

    uint32_t* ffp = (uint32_t*)d_ws;              // 7*16*512 = 57344 words
    uint32_t* embp = ffp + NUM_FF * 16 * DM;      // 512 words
    uint32_t* headp = embp + 512;                 // 512 words
    uint32_t* initp = headp + 512;                // 16 words

    pack_ff_kernel<<<(NUM_FF * 16 * DM + 255) / 256, 256, 0, stream>>>(ff, ffp);
    pack_small_kernel<<<1, 512, 0, stream>>>(embed, head, initial, embp, headp, initp);
    brnn_kernel<<<BATCH, 512, 0, stream>>>(tokens, ff_thresh, ffp, embp, headp, initp, out);
}